// Round 11
// baseline (212.903 us; speedup 1.0000x reference)
//
#include <hip/hip_runtime.h>
#include <cstdint>
#include <cstddef>

typedef __bf16 bf16_t;
typedef __bf16 bf16x8 __attribute__((ext_vector_type(8)));
typedef __bf16 bf16x4 __attribute__((ext_vector_type(4)));
typedef float f32x4 __attribute__((ext_vector_type(4)));

static constexpr int SEQ = 2048;
static constexpr int DMODEL = 1024;
static constexpr int HEADS = 16;
static constexpr int DK = 64;
static constexpr int MROWS = 4 * SEQ;               // B*S = 8192
static constexpr size_t NEC = (size_t)MROWS * DMODEL; // 8M elems
static constexpr size_t WEC = (size_t)DMODEL * DMODEL; // 1M elems

// ---------------- fp32 -> bf16 cast for the 4 weight matrices only ----------------
__global__ __launch_bounds__(256) void cast_w(const float* __restrict__ wq,
                                              const float* __restrict__ wk,
                                              const float* __restrict__ wv,
                                              const float* __restrict__ wo,
                                              bf16_t* __restrict__ out) {
  size_t i = (size_t)blockIdx.x * 256 + threadIdx.x;
  size_t e = i * 8;
  const float* src;
  size_t off;
  if (e < WEC) { src = wq; off = e; }
  else if (e < 2 * WEC) { src = wk; off = e - WEC; }
  else if (e < 3 * WEC) { src = wv; off = e - 2 * WEC; }
  else { src = wo; off = e - 3 * WEC; }
  const float4* p = reinterpret_cast<const float4*>(src + off);
  float4 a = p[0], b = p[1];
  bf16x8 o;
  o[0] = (bf16_t)a.x; o[1] = (bf16_t)a.y; o[2] = (bf16_t)a.z; o[3] = (bf16_t)a.w;
  o[4] = (bf16_t)b.x; o[5] = (bf16_t)b.y; o[6] = (bf16_t)b.z; o[7] = (bf16_t)b.w;
  *(reinterpret_cast<bf16x8*>(out + e)) = o;
}

// ---------------- async global -> LDS, 16B per lane ----------------
__device__ __forceinline__ void async16(const bf16_t* g, bf16_t* l) {
  __builtin_amdgcn_global_load_lds((const __attribute__((address_space(1))) void*)g,
                                   (__attribute__((address_space(3))) void*)l,
                                   16, 0, 0);
}

// Conflict-free LDS addressing for [rows][32]-elem bf16 K-tiles (main loop):
// view as [rows/2][64 elems], slot s3 = ((m&1)<<2)|kgroup, s3 ^= (lrow&7).
__device__ __forceinline__ int lds_off(int m, int l4) {
  int lr = m >> 1;
  return lr * 64 + (((((m & 1) << 2) | l4) ^ (lr & 7)) << 3);
}

// ================= merged Q/K/V projection GEMM, 128x256 tile =================
// A (activations) reg-staged from fp32 inputs with TWO-iteration prefetch
// distance (even-odd unrolled loop, named register pairs): loads for tile t+2
// issue at iter t, cvt+ds_write at iter t for tile t+1 -> >1000cy of compute
// covers HBM latency (R10's 1-iter distance left it partially exposed).
// B (weights, pre-cast bf16) via global_load_lds. Same swizzled LDS layout,
// 1 barrier/K-step, coalesced LDS-repack epilogue (R9).
__global__ __launch_bounds__(512, 4) void gemm_qkv(const float* __restrict__ Aq,
                                                   const float* __restrict__ Ak,
                                                   const float* __restrict__ Av,
                                                   const bf16_t* __restrict__ Wbase,
                                                   const float* __restrict__ bq,
                                                   const float* __restrict__ bk,
                                                   const float* __restrict__ bv,
                                                   float scaleQ,
                                                   bf16_t* __restrict__ QKbase,
                                                   bf16_t* __restrict__ Vt) {
  __shared__ __align__(16) bf16_t smem[24576]; // 48KB: sA[2][4096] | sB[2][8192]
  bf16_t* sAb = smem;
  bf16_t* sBb = smem + 8192;
  const int tid = threadIdx.x;
  const int lane = tid & 63;
  const int w = tid >> 6;            // 0..7
  const int wm = w >> 2, wn = w & 3; // 2 x 4 wave grid
  const int l16 = lane & 15, l4 = lane >> 4;

  // XCD-chunked bijective swizzle (768 = 8 * 96)
  int bid = blockIdx.x;
  int swz = (bid & 7) * 96 + (bid >> 3);
  const int seg = swz >> 8;    // 0,1,2 (256 tiles per seg)
  const int inner = swz & 255;
  const float* Afp = seg == 0 ? Aq : (seg == 1 ? Ak : Av);
  const bf16_t* Bw = Wbase + (size_t)seg * WEC;
  const float* bias = seg == 0 ? bq : (seg == 1 ? bk : bv);
  const float scale = seg == 0 ? scaleQ : 1.0f;
  const int bm = inner >> 2, bn = inner & 3; // 64 x 4 tiles
  const int m0 = bm << 7, n0 = bn << 8;

  // staging source mapping (thread-fixed): lane covers LDS linear bytes
  // w*1024 + lane*16 (elems: w*512 + lane*8)
  const int sg = (lane & 7) ^ ((lane >> 3) & 7);
  const int mS = 2 * (w * 8 + (lane >> 3)) + (sg >> 2); // tile row 0..127
  const int gS = (sg & 3) * 8;                           // k offset (elems)

  f32x4 acc[4][4] = {};
  float4 rA0, rA1, rB0, rB1; // two in-flight fp32 A chunks (named, rule #20)

  auto loadA = [&](float4& r0, float4& r1, int k0) {
    const float* p = Afp + (size_t)(m0 + mS) * DMODEL + k0 + gS;
    r0 = *reinterpret_cast<const float4*>(p);
    r1 = *reinterpret_cast<const float4*>(p + 4);
  };
  auto writeA = [&](int bb, const float4& r0, const float4& r1) {
    bf16x8 o;
    o[0] = (bf16_t)r0.x; o[1] = (bf16_t)r0.y; o[2] = (bf16_t)r0.z; o[3] = (bf16_t)r0.w;
    o[4] = (bf16_t)r1.x; o[5] = (bf16_t)r1.y; o[6] = (bf16_t)r1.z; o[7] = (bf16_t)r1.w;
    *reinterpret_cast<bf16x8*>(&sAb[bb * 4096 + w * 512 + lane * 8]) = o;
  };
  auto stageB = [&](int bb, int k0) {
    async16(Bw + (size_t)(n0 + mS) * DMODEL + k0 + gS, &sBb[bb * 8192 + w * 512]);
    async16(Bw + (size_t)(n0 + 128 + mS) * DMODEL + k0 + gS, &sBb[bb * 8192 + 4096 + w * 512]);
  };
  auto computeT = [&](int bb) {
    const bf16_t* bA = &sAb[bb * 4096];
    const bf16_t* bB = &sBb[bb * 8192];
    bf16x8 af[4], bf[4];
#pragma unroll
    for (int f = 0; f < 4; ++f)
      af[f] = *reinterpret_cast<const bf16x8*>(&bA[lds_off(wm * 64 + f * 16 + l16, l4)]);
#pragma unroll
    for (int j = 0; j < 4; ++j)
      bf[j] = *reinterpret_cast<const bf16x8*>(&bB[lds_off(wn * 64 + j * 16 + l16, l4)]);
    __builtin_amdgcn_s_setprio(1);
#pragma unroll
    for (int i = 0; i < 4; ++i)
#pragma unroll
      for (int j = 0; j < 4; ++j)
        acc[i][j] = __builtin_amdgcn_mfma_f32_16x16x32_bf16(af[i], bf[j], acc[i][j], 0, 0, 0);
    __builtin_amdgcn_s_setprio(0);
  };

  const int NKT = DMODEL / 32; // 32, even
  // prologue: tile0 A through regs; tile1 A issued (hidden under barrier+compute)
  loadA(rA0, rA1, 0);
  stageB(0, 0);
  writeA(0, rA0, rA1);
  loadA(rB0, rB1, 32);
  __syncthreads();
  for (int t = 0; t < NKT; t += 2) {
    // even body: compute tile t (buf0)
    if (t + 2 < NKT) loadA(rA0, rA1, (t + 2) * 32);
    if (t + 1 < NKT) stageB(1, (t + 1) * 32);
    computeT(0);
    if (t + 1 < NKT) writeA(1, rB0, rB1); // loaded 2 phases ago -> latency hidden
    __syncthreads();
    // odd body: compute tile t+1 (buf1)
    if (t + 3 < NKT) loadA(rB0, rB1, (t + 3) * 32);
    if (t + 2 < NKT) stageB(0, (t + 2) * 32);
    computeT(1);
    if (t + 2 < NKT) writeA(0, rA0, rA1);
    __syncthreads();
  }
  // Epilogue: wave-local LDS repack (no barriers; smem free after final barrier)

  float bj[4];
#pragma unroll
  for (int j = 0; j < 4; ++j) bj[j] = bias[n0 + wn * 64 + j * 16 + l16];

  const int hglob = bn * 4 + wn;           // each wave owns exactly one head
  bf16_t* patch = smem + w * 3072;         // 6KB per wave

  if (seg < 2) {
    bf16_t* outQK = QKbase + (size_t)seg * NEC;
#pragma unroll
    for (int h2 = 0; h2 < 2; ++h2) {
#pragma unroll
      for (int ii = 0; ii < 2; ++ii) {
        int i = h2 * 2 + ii;
#pragma unroll
        for (int j = 0; j < 4; ++j) {
#pragma unroll
          for (int r = 0; r < 4; ++r) {
            float v = (acc[i][j][r] + bj[j]) * scale;
            patch[(ii * 16 + l4 * 4 + r) * 72 + j * 16 + l16] = (bf16_t)v;
          }
        }
      }
#pragma unroll
      for (int kk = 0; kk < 4; ++kk) {
        int row = kk * 8 + (lane >> 3);
        int doff = (lane & 7) * 8;
        bf16x8 ch = *reinterpret_cast<const bf16x8*>(&patch[row * 72 + doff]);
        int m = m0 + wm * 64 + h2 * 32 + row;
        int b = m >> 11, s = m & 2047;
        *reinterpret_cast<bf16x8*>(
            &outQK[(((size_t)(b * HEADS + hglob) * SEQ + s) << 6) + doff]) = ch;
      }
    }
  } else {
    // V: transpose to [B,H,dk,S] via [64 d][48] padded patch (96B rows)
#pragma unroll
    for (int h2 = 0; h2 < 2; ++h2) {
#pragma unroll
      for (int ii = 0; ii < 2; ++ii) {
        int i = h2 * 2 + ii;
#pragma unroll
        for (int j = 0; j < 4; ++j) {
          bf16x4 pk;
#pragma unroll
          for (int r = 0; r < 4; ++r) pk[r] = (bf16_t)(acc[i][j][r] + bj[j]);
          *reinterpret_cast<bf16x4*>(
              &patch[(j * 16 + l16) * 48 + ii * 16 + l4 * 4]) = pk;
        }
      }
#pragma unroll
      for (int kk = 0; kk < 4; ++kk) {
        int d = kk * 16 + (lane >> 2);
        int soff = (lane & 3) * 8;
        bf16x8 ch = *reinterpret_cast<const bf16x8*>(&patch[d * 48 + soff]);
        int m = m0 + wm * 64 + h2 * 32;
        int b = m >> 11, s = (m & 2047) + soff;
        *reinterpret_cast<bf16x8*>(
            &Vt[((size_t)(b * HEADS + hglob) * DK + d) * SEQ + s]) = ch;
      }
    }
  }
}

// ================= final output projection: fp32 out, 128x128 tile =================
// A (attention output, bf16) fragments loaded DIRECTLY from global with
// 1-iter prefetch (L2-served: 8 consecutive same-XCD bn-blocks reuse panels).
// Only B staged in LDS (16KB double-buffered) -> more co-resident blocks.
__global__ __launch_bounds__(256, 4) void gemm_out(const bf16_t* __restrict__ A,
                                                   const bf16_t* __restrict__ Bw,
                                                   const float* __restrict__ bias,
                                                   float* __restrict__ Cout) {
  __shared__ __align__(16) bf16_t sB[2][128 * 32]; // [64][64] swizzled view
  const int tid = threadIdx.x;
  const int lane = tid & 63;
  const int wv = tid >> 6; // 0..3
  const int l16 = lane & 15, l4 = lane >> 4;

  int bid = blockIdx.x;
  int swz = (bid & 7) * 64 + (bid >> 3); // 512 = 8 * 64
  const int bm = swz >> 3, bn = swz & 7;
  const int m0 = bm << 7, n0 = bn << 7;
  const int wr = (wv >> 1) * 64, wc = (wv & 1) * 64;

  const int sg = (lane & 7) ^ ((lane >> 3) & 7);
  const int mS = 2 * (wv * 8 + (lane >> 3)) + (sg >> 2); // + c*64
  const int gS = (sg & 3) * 8;

  f32x4 acc[4][4] = {};
  bf16x8 afE[4], afO[4]; // even/odd A-fragment sets (named, rule #20)

  auto loadAf = [&](bf16x8* af, int k0) {
#pragma unroll
    for (int f = 0; f < 4; ++f)
      af[f] = *reinterpret_cast<const bf16x8*>(
          &A[(size_t)(m0 + wr + f * 16 + l16) * DMODEL + k0 + l4 * 8]);
  };
  auto stageB = [&](int bb, int k0) {
#pragma unroll
    for (int c = 0; c < 2; ++c)
      async16(Bw + (size_t)(n0 + c * 64 + mS) * DMODEL + k0 + gS, &sB[bb][c * 2048 + wv * 512]);
  };
  auto computeT = [&](const bf16x8* af, int bb) {
    bf16x8 bf[4];
#pragma unroll
    for (int j = 0; j < 4; ++j)
      bf[j] = *reinterpret_cast<const bf16x8*>(&sB[bb][lds_off(wc + j * 16 + l16, l4)]);
    __builtin_amdgcn_s_setprio(1);
#pragma unroll
    for (int i = 0; i < 4; ++i)
#pragma unroll
      for (int j = 0; j < 4; ++j)
        acc[i][j] = __builtin_amdgcn_mfma_f32_16x16x32_bf16(af[i], bf[j], acc[i][j], 0, 0, 0);
    __builtin_amdgcn_s_setprio(0);
  };

  const int NKT = DMODEL / 32; // 32, even
  loadAf(afE, 0);
  stageB(0, 0);
  __syncthreads();
  for (int t = 0; t < NKT; t += 2) {
    if (t + 1 < NKT) {
      loadAf(afO, (t + 1) * 32);
      stageB(1, (t + 1) * 32);
    }
    computeT(afE, 0);
    __syncthreads();
    if (t + 2 < NKT) {
      loadAf(afE, (t + 2) * 32);
      stageB(0, (t + 2) * 32);
    }
    computeT(afO, 1);
    __syncthreads();
  }

  float bj[4];
#pragma unroll
  for (int j = 0; j < 4; ++j) bj[j] = bias[n0 + wc + j * 16 + l16];

#pragma unroll
  for (int i = 0; i < 4; ++i) {
#pragma unroll
    for (int j = 0; j < 4; ++j) {
#pragma unroll
      for (int r = 0; r < 4; ++r) {
        int m = m0 + wr + i * 16 + l4 * 4 + r;
        int n = n0 + wc + j * 16 + l16;
        Cout[(size_t)m * DMODEL + n] = acc[i][j][r] + bj[j];
      }
    }
  }
}

// ---------------- flash attention (unchanged from R4) ----------------
__device__ __forceinline__ int kvsrc_row(int r) {
  return (r & 32) | (((r >> 3) & 1) << 4) | (((r >> 2) & 1) << 3) |
         (((r >> 4) & 1) << 2) | (r & 3);
}

__global__ __launch_bounds__(512, 2) void attn_kernel(const bf16_t* __restrict__ Q,
                                                      const bf16_t* __restrict__ Kp,
                                                      const bf16_t* __restrict__ Vt,
                                                      bf16_t* __restrict__ AO) {
  __shared__ __align__(16) bf16_t sK[2][64 * 64];
  __shared__ __align__(16) bf16_t sV[2][64 * 64];
  const int tid = threadIdx.x;
  const int lane = tid & 63;
  const int wv = tid >> 6; // 0..7
  const int l16 = lane & 15, l4 = lane >> 4;
  const int sub8 = lane >> 3, c8 = lane & 7;

  const int nq = SEQ / 256; // 8
  int bid = blockIdx.x;
  int swz = (bid & 7) * 64 + (bid >> 3); // 512 blocks, bijective
  const int bh = swz / nq, qt = swz % nq;
  const int b = bh >> 4, h = bh & 15;
  const bf16_t* Qh = Q + (size_t)bh * SEQ * DK;
  const bf16_t* Kh = Kp + (size_t)bh * SEQ * DK;
  const bf16_t* Vh = Vt + (size_t)bh * DK * SEQ;
  const int q0 = qt * 256 + wv * 32;

  bf16x8 aq[2][2];
#pragma unroll
  for (int s = 0; s < 2; ++s)
#pragma unroll
    for (int hf = 0; hf < 2; ++hf)
      aq[s][hf] = *reinterpret_cast<const bf16x8*>(
          &Qh[(size_t)(q0 + s * 16 + l16) * DK + hf * 32 + l4 * 8]);

  bf16x8 ones;
#pragma unroll
  for (int i = 0; i < 8; ++i) ones[i] = (bf16_t)1.0f;

  f32x4 o[2][4] = {};
  f32x4 lacc[2] = {};

  auto stage = [&](int buf, int kv0) {
    int r = wv * 8 + sub8;
    int kvr = kvsrc_row(r);
    int cs = (c8 ^ sub8) << 3;
    async16(Kh + (size_t)(kv0 + kvr) * DK + cs, &sK[buf][wv * 512]);
    async16(Vh + (size_t)r * SEQ + kv0 + cs, &sV[buf][wv * 512]);
  };

  auto compute = [&](int buf) {
    const bf16_t* bK = sK[buf];
    const bf16_t* bV = sV[buf];
    f32x4 sc[2][4] = {};
    __builtin_amdgcn_s_setprio(1);
#pragma unroll
    for (int t = 0; t < 4; ++t) {
      bf16x8 kf0 = *reinterpret_cast<const bf16x8*>(
          &bK[(t * 16 + l16) * 64 + ((l4 ^ (l16 & 7)) << 3)]);
      bf16x8 kf1 = *reinterpret_cast<const bf16x8*>(
          &bK[(t * 16 + l16) * 64 + (((4 + l4) ^ (l16 & 7)) << 3)]);
#pragma unroll
      for (int s = 0; s < 2; ++s) {
        sc[s][t] = __builtin_amdgcn_mfma_f32_16x16x32_bf16(kf0, aq[s][0], sc[s][t], 0, 0, 0);
        sc[s][t] = __builtin_amdgcn_mfma_f32_16x16x32_bf16(kf1, aq[s][1], sc[s][t], 0, 0, 0);
      }
    }
    __builtin_amdgcn_s_setprio(0);
    bf16x8 pa[2][2];
#pragma unroll
    for (int s = 0; s < 2; ++s) {
#pragma unroll
      for (int t = 0; t < 4; ++t) {
#pragma unroll
        for (int j = 0; j < 4; ++j) {
          pa[s][t >> 1][(t & 1) * 4 + j] = (bf16_t)__builtin_amdgcn_exp2f(sc[s][t][j]);
        }
      }
    }
    __builtin_amdgcn_s_setprio(1);
#pragma unroll
    for (int nb = 0; nb < 4; ++nb) {
      bf16x8 vf0 = *reinterpret_cast<const bf16x8*>(
          &bV[(nb * 16 + l16) * 64 + ((l4 ^ (l16 & 7)) << 3)]);
      bf16x8 vf1 = *reinterpret_cast<const bf16x8*>(
          &bV[(nb * 16 + l16) * 64 + (((4 + l4) ^ (l16 & 7)) << 3)]);
#pragma unroll
      for (int s = 0; s < 2; ++s) {
        o[s][nb] = __builtin_amdgcn_mfma_f32_16x16x32_bf16(pa[s][0], vf0, o[s][nb], 0, 0, 0);
        o[s][nb] = __builtin_amdgcn_mfma_f32_16x16x32_bf16(pa[s][1], vf1, o[s][nb], 0, 0, 0);
      }
    }
#pragma unroll
    for (int s = 0; s < 2; ++s) {
      lacc[s] = __builtin_amdgcn_mfma_f32_16x16x32_bf16(pa[s][0], ones, lacc[s], 0, 0, 0);
      lacc[s] = __builtin_amdgcn_mfma_f32_16x16x32_bf16(pa[s][1], ones, lacc[s], 0, 0, 0);
    }
    __builtin_amdgcn_s_setprio(0);
  };

  stage(0, 0);
  __syncthreads();
  const int NT = SEQ / 64; // 32
  for (int it = 0; it < NT; ++it) {
    if (it + 1 < NT) stage((it + 1) & 1, (it + 1) * 64);
    compute(it & 1);
    __syncthreads();
  }

#pragma unroll
  for (int s = 0; s < 2; ++s) {
#pragma unroll
    for (int j = 0; j < 4; ++j) {
      float inv = 1.0f / lacc[s][j];
      int qrow = q0 + s * 16 + l4 * 4 + j;
#pragma unroll
      for (int nb = 0; nb < 4; ++nb)
        AO[((size_t)(b * SEQ + qrow)) * DMODEL + h * DK + nb * 16 + l16] =
            (bf16_t)(o[s][nb][j] * inv);
    }
  }
}

// ---------------- launcher ----------------
extern "C" void kernel_launch(void* const* d_in, const int* in_sizes, int n_in,
                              void* d_out, int out_size, void* d_ws, size_t ws_size,
                              hipStream_t stream) {
  const float* query = (const float*)d_in[0];
  const float* key_i = (const float*)d_in[1];
  const float* value = (const float*)d_in[2];
  const float* Wq = (const float*)d_in[3];
  const float* bq = (const float*)d_in[4];
  const float* Wk = (const float*)d_in[5];
  const float* bk = (const float*)d_in[6];
  const float* Wv = (const float*)d_in[7];
  const float* bv = (const float*)d_in[8];
  const float* Wo = (const float*)d_in[9];
  const float* bo = (const float*)d_in[10];
  float* out = (float*)d_out;

  bf16_t* wqb = (bf16_t*)d_ws;      // wqb|wkb|wvb|wob contiguous (W segments)
  bf16_t* wob = wqb + 3 * WEC;
  bf16_t* Qp = wob + WEC;           // Qp|Kp contiguous (QK output segments)
  bf16_t* Kp = Qp + NEC;
  bf16_t* Vt = Kp + NEC;
  bf16_t* AO = Vt + NEC;
  // workspace: (4*WEC + 4*NEC)*2 = 72 MiB

  cast_w<<<dim3((unsigned)(4 * WEC / 8 / 256)), dim3(256), 0, stream>>>(
      Wq, Wk, Wv, Wo, wqb);

  const float cexp = 0.18033688f; // log2(e)/8, folded into Q projection
  gemm_qkv<<<dim3(768), dim3(512), 0, stream>>>(query, key_i, value, wqb,
                                                bq, bk, bv, cexp, Qp, Vt);

  attn_kernel<<<dim3(4 * HEADS * (SEQ / 256)), 512, 0, stream>>>(Qp, Kp, Vt, AO);

  gemm_out<<<dim3(512), dim3(256), 0, stream>>>(AO, wob, bo, out);
}

// Round 12
// 166.444 us; speedup vs baseline: 1.2791x; 1.2791x over previous
//
#include <hip/hip_runtime.h>
#include <cstdint>
#include <cstddef>

typedef __bf16 bf16_t;
typedef __bf16 bf16x8 __attribute__((ext_vector_type(8)));
typedef __bf16 bf16x4 __attribute__((ext_vector_type(4)));
typedef float f32x4 __attribute__((ext_vector_type(4)));

static constexpr int SEQ = 2048;
static constexpr int DMODEL = 1024;
static constexpr int HEADS = 16;
static constexpr int DK = 64;
static constexpr int MROWS = 4 * SEQ;               // B*S = 8192
static constexpr size_t NEC = (size_t)MROWS * DMODEL; // 8M elems
static constexpr size_t WEC = (size_t)DMODEL * DMODEL; // 1M elems

// ---------------- fp32 -> bf16 cast for the 4 weight matrices only ----------------
__global__ __launch_bounds__(256) void cast_w(const float* __restrict__ wq,
                                              const float* __restrict__ wk,
                                              const float* __restrict__ wv,
                                              const float* __restrict__ wo,
                                              bf16_t* __restrict__ out) {
  size_t i = (size_t)blockIdx.x * 256 + threadIdx.x;
  size_t e = i * 8;
  const float* src;
  size_t off;
  if (e < WEC) { src = wq; off = e; }
  else if (e < 2 * WEC) { src = wk; off = e - WEC; }
  else if (e < 3 * WEC) { src = wv; off = e - 2 * WEC; }
  else { src = wo; off = e - 3 * WEC; }
  const float4* p = reinterpret_cast<const float4*>(src + off);
  float4 a = p[0], b = p[1];
  bf16x8 o;
  o[0] = (bf16_t)a.x; o[1] = (bf16_t)a.y; o[2] = (bf16_t)a.z; o[3] = (bf16_t)a.w;
  o[4] = (bf16_t)b.x; o[5] = (bf16_t)b.y; o[6] = (bf16_t)b.z; o[7] = (bf16_t)b.w;
  *(reinterpret_cast<bf16x8*>(out + e)) = o;
}

// ---------------- async global -> LDS, 16B per lane ----------------
__device__ __forceinline__ void async16(const void* g, void* l) {
  __builtin_amdgcn_global_load_lds((const __attribute__((address_space(1))) void*)g,
                                   (__attribute__((address_space(3))) void*)l,
                                   16, 0, 0);
}

// Conflict-free LDS addressing for [rows][32]-elem bf16 tiles:
// view as [rows/2][64 elems], slot s3 = ((m&1)<<2)|kgroup, s3 ^= (lrow&7).
__device__ __forceinline__ int lds_off(int m, int l4) {
  int lr = m >> 1;
  return lr * 64 + (((((m & 1) << 2) | l4) ^ (lr & 7)) << 3);
}

// ================= merged Q/K/V projection GEMM, 128x256 tile =================
// A (activations) staged as RAW FP32 via global_load_lds (async, zero VGPRs;
// no reg-held pipeline -> no spills, R11's failure mode). fp32->bf16 conversion
// happens at fragment-read time (VALU is idle). LDS budget kept at 48KB for
// 3 blocks/CU: A fp32 double-buffered (32KB) + B bf16 SINGLE-buffered (16KB).
// B frags are pulled to registers at iter top; a cheap mid-__syncthreads (no
// VMEM outstanding at that point -> no latency exposure) publishes "B read
// done" before restaging B. All gll drains happen at the end-of-iter barrier,
// after the MFMA cluster (proven R8/R9 hiding pattern).
// A-LDS layout: [128 rows][32 fp32] = 128B rows of 8x16B slots, slot^=(row&7);
// both fragment b128 reads are 2-way (free); staging source pre-swizzled.
__global__ __launch_bounds__(512, 4) void gemm_qkv(const float* __restrict__ Aq,
                                                   const float* __restrict__ Ak,
                                                   const float* __restrict__ Av,
                                                   const bf16_t* __restrict__ Wbase,
                                                   const float* __restrict__ bq,
                                                   const float* __restrict__ bk,
                                                   const float* __restrict__ bv,
                                                   float scaleQ,
                                                   bf16_t* __restrict__ QKbase,
                                                   bf16_t* __restrict__ Vt) {
  __shared__ __align__(16) bf16_t smem[24576]; // 48KB = A fp32 2x16KB | B bf16 16KB
  float* sAf = reinterpret_cast<float*>(smem);  // 2 x 4096 floats
  bf16_t* sBb = smem + 16384;                   // 8192 bf16
  const int tid = threadIdx.x;
  const int lane = tid & 63;
  const int w = tid >> 6;            // 0..7
  const int wm = w >> 2, wn = w & 3; // 2 x 4 wave grid
  const int l16 = lane & 15, l4 = lane >> 4;
  const int sub8 = lane >> 3, c8 = lane & 7;

  // XCD-chunked bijective swizzle (768 = 8 * 96)
  int bid = blockIdx.x;
  int swz = (bid & 7) * 96 + (bid >> 3);
  const int seg = swz >> 8;    // 0,1,2 (256 tiles per seg)
  const int inner = swz & 255;
  const float* Afp = seg == 0 ? Aq : (seg == 1 ? Ak : Av);
  const bf16_t* Bw = Wbase + (size_t)seg * WEC;
  const float* bias = seg == 0 ? bq : (seg == 1 ? bk : bv);
  const float scale = seg == 0 ? scaleQ : 1.0f;
  const int bm = inner >> 2, bn = inner & 3; // 64 x 4 tiles
  const int m0 = bm << 7, n0 = bn << 8;

  // B staging source mapping (thread-fixed), bf16 path (R9-proven):
  const int sg = c8 ^ sub8;
  const int mS = 2 * (w * 8 + sub8) + (sg >> 2);  // B tile row 0..127 (+128 for chunk 2)
  const int gS = (sg & 3) * 8;                     // k offset (bf16 elems)
  // A staging (fp32): chunk c covers rows c*64 + w*8 + sub8, 16B group g = c8^sub8
  const int rA = w * 8 + sub8;                     // + c*64
  const int gA = (c8 ^ sub8) * 4;                  // fp32 elem offset (4 per 16B)

  f32x4 acc[4][4] = {};

  auto stageA = [&](int bb, int k0) {
#pragma unroll
    for (int c = 0; c < 2; ++c)
      async16(Afp + (size_t)(m0 + c * 64 + rA) * DMODEL + k0 + gA,
              sAf + bb * 4096 + c * 2048 + w * 256);
  };
  auto stageB = [&](int k0) {
    async16(Bw + (size_t)(n0 + mS) * DMODEL + k0 + gS, sBb + w * 512);
    async16(Bw + (size_t)(n0 + 128 + mS) * DMODEL + k0 + gS, sBb + 4096 + w * 512);
  };

  stageA(0, 0);
  stageB(0);
  __syncthreads(); // drain prologue staging
  const int NKT = DMODEL / 32; // 32
  for (int t = 0; t < NKT; ++t) {
    // (1) pull B frags to registers (single buffer)
    bf16x8 bf[4];
#pragma unroll
    for (int j = 0; j < 4; ++j)
      bf[j] = *reinterpret_cast<const bf16x8*>(&sBb[lds_off(wn * 64 + j * 16 + l16, l4)]);
    __syncthreads(); // B reads done block-wide; nothing vmcnt-outstanding -> cheap
    // (2) stage next tile (A -> other fp32 buf, B -> single buf)
    if (t + 1 < NKT) {
      stageA((t + 1) & 1, (t + 1) * 32);
      stageB((t + 1) * 32);
    }
    // (3) A fp32 frags from sA[t&1], convert to bf16
    const float* bA = sAf + (t & 1) * 4096;
    bf16x8 af[4];
#pragma unroll
    for (int f = 0; f < 4; ++f) {
      int R = wm * 64 + f * 16 + l16;
      int s0 = (2 * l4) ^ (R & 7);
      const float* rb = bA + R * 32;
      f32x4 a0 = *reinterpret_cast<const f32x4*>(rb + s0 * 4);
      f32x4 a1 = *reinterpret_cast<const f32x4*>(rb + (s0 ^ 1) * 4);
#pragma unroll
      for (int e = 0; e < 4; ++e) { af[f][e] = (bf16_t)a0[e]; af[f][4 + e] = (bf16_t)a1[e]; }
    }
    // (4) MFMA
    __builtin_amdgcn_s_setprio(1);
#pragma unroll
    for (int i = 0; i < 4; ++i)
#pragma unroll
      for (int j = 0; j < 4; ++j)
        acc[i][j] = __builtin_amdgcn_mfma_f32_16x16x32_bf16(af[i], bf[j], acc[i][j], 0, 0, 0);
    __builtin_amdgcn_s_setprio(0);
    __syncthreads(); // drains next-tile glls (hidden under steps 3-4)
  }
  // Epilogue: wave-local LDS repack (no barriers; smem free after final barrier)

  float bj[4];
#pragma unroll
  for (int j = 0; j < 4; ++j) bj[j] = bias[n0 + wn * 64 + j * 16 + l16];

  const int hglob = bn * 4 + wn;           // each wave owns exactly one head
  bf16_t* patch = smem + w * 3072;         // 6KB per wave

  if (seg < 2) {
    bf16_t* outQK = QKbase + (size_t)seg * NEC;
#pragma unroll
    for (int h2 = 0; h2 < 2; ++h2) {
#pragma unroll
      for (int ii = 0; ii < 2; ++ii) {
        int i = h2 * 2 + ii;
#pragma unroll
        for (int j = 0; j < 4; ++j) {
#pragma unroll
          for (int r = 0; r < 4; ++r) {
            float v = (acc[i][j][r] + bj[j]) * scale;
            patch[(ii * 16 + l4 * 4 + r) * 72 + j * 16 + l16] = (bf16_t)v;
          }
        }
      }
#pragma unroll
      for (int kk = 0; kk < 4; ++kk) {
        int row = kk * 8 + sub8;
        int doff = c8 * 8;
        bf16x8 ch = *reinterpret_cast<const bf16x8*>(&patch[row * 72 + doff]);
        int m = m0 + wm * 64 + h2 * 32 + row;
        int b = m >> 11, s = m & 2047;
        *reinterpret_cast<bf16x8*>(
            &outQK[(((size_t)(b * HEADS + hglob) * SEQ + s) << 6) + doff]) = ch;
      }
    }
  } else {
    // V: transpose to [B,H,dk,S] via [64 d][48] padded patch (96B rows)
#pragma unroll
    for (int h2 = 0; h2 < 2; ++h2) {
#pragma unroll
      for (int ii = 0; ii < 2; ++ii) {
        int i = h2 * 2 + ii;
#pragma unroll
        for (int j = 0; j < 4; ++j) {
          bf16x4 pk;
#pragma unroll
          for (int r = 0; r < 4; ++r) pk[r] = (bf16_t)(acc[i][j][r] + bj[j]);
          *reinterpret_cast<bf16x4*>(
              &patch[(j * 16 + l16) * 48 + ii * 16 + l4 * 4]) = pk;
        }
      }
#pragma unroll
      for (int kk = 0; kk < 4; ++kk) {
        int d = kk * 16 + (lane >> 2);
        int soff = (lane & 3) * 8;
        bf16x8 ch = *reinterpret_cast<const bf16x8*>(&patch[d * 48 + soff]);
        int m = m0 + wm * 64 + h2 * 32;
        int b = m >> 11, s = (m & 2047) + soff;
        *reinterpret_cast<bf16x8*>(
            &Vt[((size_t)(b * HEADS + hglob) * DK + d) * SEQ + s]) = ch;
      }
    }
  }
}

// ================= final output projection: fp32 out, 128x128 tile =================
// (exact R9/R10 form: both operands via global_load_lds, 2-phase dbuf loop)
__global__ __launch_bounds__(256, 4) void gemm_out(const bf16_t* __restrict__ A,
                                                   const bf16_t* __restrict__ Bw,
                                                   const float* __restrict__ bias,
                                                   float* __restrict__ Cout) {
  __shared__ __align__(16) bf16_t sA[2][128 * 32]; // [64][64] swizzled view
  __shared__ __align__(16) bf16_t sB[2][128 * 32];
  const int tid = threadIdx.x;
  const int lane = tid & 63;
  const int wv = tid >> 6; // 0..3
  const int l16 = lane & 15, l4 = lane >> 4;

  int bid = blockIdx.x;
  int swz = (bid & 7) * 64 + (bid >> 3); // 512 = 8 * 64
  const int bm = swz >> 3, bn = swz & 7;
  const int m0 = bm << 7, n0 = bn << 7;
  const int wr = (wv >> 1) * 64, wc = (wv & 1) * 64;

  const int sg = (lane & 7) ^ ((lane >> 3) & 7);
  const int mS = 2 * (wv * 8 + (lane >> 3)) + (sg >> 2); // + c*64
  const int gS = (sg & 3) * 8;

  f32x4 acc[4][4] = {};

  auto stage = [&](int bb, int k0) {
#pragma unroll
    for (int c = 0; c < 2; ++c) {
      async16(A + (size_t)(m0 + c * 64 + mS) * DMODEL + k0 + gS, &sA[bb][c * 2048 + wv * 512]);
      async16(Bw + (size_t)(n0 + c * 64 + mS) * DMODEL + k0 + gS, &sB[bb][c * 2048 + wv * 512]);
    }
  };

  stage(0, 0);
  __syncthreads();
  const int NKT = DMODEL / 32; // 32
  for (int t = 0; t < NKT; ++t) {
    if (t + 1 < NKT) stage((t + 1) & 1, (t + 1) * 32);
    const bf16_t* bA = sA[t & 1];
    const bf16_t* bB = sB[t & 1];
    bf16x8 afrag[4], bfrag[4];
#pragma unroll
    for (int f = 0; f < 4; ++f) {
      afrag[f] = *reinterpret_cast<const bf16x8*>(&bA[lds_off(wr + f * 16 + l16, l4)]);
      bfrag[f] = *reinterpret_cast<const bf16x8*>(&bB[lds_off(wc + f * 16 + l16, l4)]);
    }
    __builtin_amdgcn_s_setprio(1);
#pragma unroll
    for (int i = 0; i < 4; ++i)
#pragma unroll
      for (int j = 0; j < 4; ++j)
        acc[i][j] = __builtin_amdgcn_mfma_f32_16x16x32_bf16(afrag[i], bfrag[j], acc[i][j], 0, 0, 0);
    __builtin_amdgcn_s_setprio(0);
    __syncthreads();
  }

  float bj[4];
#pragma unroll
  for (int j = 0; j < 4; ++j) bj[j] = bias[n0 + wc + j * 16 + l16];

#pragma unroll
  for (int i = 0; i < 4; ++i) {
#pragma unroll
    for (int j = 0; j < 4; ++j) {
#pragma unroll
      for (int r = 0; r < 4; ++r) {
        int m = m0 + wr + i * 16 + l4 * 4 + r;
        int n = n0 + wc + j * 16 + l16;
        Cout[(size_t)m * DMODEL + n] = acc[i][j][r] + bj[j];
      }
    }
  }
}

// ---------------- flash attention (unchanged from R4) ----------------
__device__ __forceinline__ int kvsrc_row(int r) {
  return (r & 32) | (((r >> 3) & 1) << 4) | (((r >> 2) & 1) << 3) |
         (((r >> 4) & 1) << 2) | (r & 3);
}

__global__ __launch_bounds__(512, 2) void attn_kernel(const bf16_t* __restrict__ Q,
                                                      const bf16_t* __restrict__ Kp,
                                                      const bf16_t* __restrict__ Vt,
                                                      bf16_t* __restrict__ AO) {
  __shared__ __align__(16) bf16_t sK[2][64 * 64];
  __shared__ __align__(16) bf16_t sV[2][64 * 64];
  const int tid = threadIdx.x;
  const int lane = tid & 63;
  const int wv = tid >> 6; // 0..7
  const int l16 = lane & 15, l4 = lane >> 4;
  const int sub8 = lane >> 3, c8 = lane & 7;

  const int nq = SEQ / 256; // 8
  int bid = blockIdx.x;
  int swz = (bid & 7) * 64 + (bid >> 3); // 512 blocks, bijective
  const int bh = swz / nq, qt = swz % nq;
  const int b = bh >> 4, h = bh & 15;
  const bf16_t* Qh = Q + (size_t)bh * SEQ * DK;
  const bf16_t* Kh = Kp + (size_t)bh * SEQ * DK;
  const bf16_t* Vh = Vt + (size_t)bh * DK * SEQ;
  const int q0 = qt * 256 + wv * 32;

  bf16x8 aq[2][2];
#pragma unroll
  for (int s = 0; s < 2; ++s)
#pragma unroll
    for (int hf = 0; hf < 2; ++hf)
      aq[s][hf] = *reinterpret_cast<const bf16x8*>(
          &Qh[(size_t)(q0 + s * 16 + l16) * DK + hf * 32 + l4 * 8]);

  bf16x8 ones;
#pragma unroll
  for (int i = 0; i < 8; ++i) ones[i] = (bf16_t)1.0f;

  f32x4 o[2][4] = {};
  f32x4 lacc[2] = {};

  auto stage = [&](int buf, int kv0) {
    int r = wv * 8 + sub8;
    int kvr = kvsrc_row(r);
    int cs = (c8 ^ sub8) << 3;
    async16(Kh + (size_t)(kv0 + kvr) * DK + cs, &sK[buf][wv * 512]);
    async16(Vh + (size_t)r * SEQ + kv0 + cs, &sV[buf][wv * 512]);
  };

  auto compute = [&](int buf) {
    const bf16_t* bK = sK[buf];
    const bf16_t* bV = sV[buf];
    f32x4 sc[2][4] = {};
    __builtin_amdgcn_s_setprio(1);
#pragma unroll
    for (int t = 0; t < 4; ++t) {
      bf16x8 kf0 = *reinterpret_cast<const bf16x8*>(
          &bK[(t * 16 + l16) * 64 + ((l4 ^ (l16 & 7)) << 3)]);
      bf16x8 kf1 = *reinterpret_cast<const bf16x8*>(
          &bK[(t * 16 + l16) * 64 + (((4 + l4) ^ (l16 & 7)) << 3)]);
#pragma unroll
      for (int s = 0; s < 2; ++s) {
        sc[s][t] = __builtin_amdgcn_mfma_f32_16x16x32_bf16(kf0, aq[s][0], sc[s][t], 0, 0, 0);
        sc[s][t] = __builtin_amdgcn_mfma_f32_16x16x32_bf16(kf1, aq[s][1], sc[s][t], 0, 0, 0);
      }
    }
    __builtin_amdgcn_s_setprio(0);
    bf16x8 pa[2][2];
#pragma unroll
    for (int s = 0; s < 2; ++s) {
#pragma unroll
      for (int t = 0; t < 4; ++t) {
#pragma unroll
        for (int j = 0; j < 4; ++j) {
          pa[s][t >> 1][(t & 1) * 4 + j] = (bf16_t)__builtin_amdgcn_exp2f(sc[s][t][j]);
        }
      }
    }
    __builtin_amdgcn_s_setprio(1);
#pragma unroll
    for (int nb = 0; nb < 4; ++nb) {
      bf16x8 vf0 = *reinterpret_cast<const bf16x8*>(
          &bV[(nb * 16 + l16) * 64 + ((l4 ^ (l16 & 7)) << 3)]);
      bf16x8 vf1 = *reinterpret_cast<const bf16x8*>(
          &bV[(nb * 16 + l16) * 64 + (((4 + l4) ^ (l16 & 7)) << 3)]);
#pragma unroll
      for (int s = 0; s < 2; ++s) {
        o[s][nb] = __builtin_amdgcn_mfma_f32_16x16x32_bf16(pa[s][0], vf0, o[s][nb], 0, 0, 0);
        o[s][nb] = __builtin_amdgcn_mfma_f32_16x16x32_bf16(pa[s][1], vf1, o[s][nb], 0, 0, 0);
      }
    }
#pragma unroll
    for (int s = 0; s < 2; ++s) {
      lacc[s] = __builtin_amdgcn_mfma_f32_16x16x32_bf16(pa[s][0], ones, lacc[s], 0, 0, 0);
      lacc[s] = __builtin_amdgcn_mfma_f32_16x16x32_bf16(pa[s][1], ones, lacc[s], 0, 0, 0);
    }
    __builtin_amdgcn_s_setprio(0);
  };

  stage(0, 0);
  __syncthreads();
  const int NT = SEQ / 64; // 32
  for (int it = 0; it < NT; ++it) {
    if (it + 1 < NT) stage((it + 1) & 1, (it + 1) * 64);
    compute(it & 1);
    __syncthreads();
  }

#pragma unroll
  for (int s = 0; s < 2; ++s) {
#pragma unroll
    for (int j = 0; j < 4; ++j) {
      float inv = 1.0f / lacc[s][j];
      int qrow = q0 + s * 16 + l4 * 4 + j;
#pragma unroll
      for (int nb = 0; nb < 4; ++nb)
        AO[((size_t)(b * SEQ + qrow)) * DMODEL + h * DK + nb * 16 + l16] =
            (bf16_t)(o[s][nb][j] * inv);
    }
  }
}

// ---------------- launcher ----------------
extern "C" void kernel_launch(void* const* d_in, const int* in_sizes, int n_in,
                              void* d_out, int out_size, void* d_ws, size_t ws_size,
                              hipStream_t stream) {
  const float* query = (const float*)d_in[0];
  const float* key_i = (const float*)d_in[1];
  const float* value = (const float*)d_in[2];
  const float* Wq = (const float*)d_in[3];
  const float* bq = (const float*)d_in[4];
  const float* Wk = (const float*)d_in[5];
  const float* bk = (const float*)d_in[6];
  const float* Wv = (const float*)d_in[7];
  const float* bv = (const float*)d_in[8];
  const float* Wo = (const float*)d_in[9];
  const float* bo = (const float*)d_in[10];
  float* out = (float*)d_out;

  bf16_t* wqb = (bf16_t*)d_ws;      // wqb|wkb|wvb|wob contiguous (W segments)
  bf16_t* wob = wqb + 3 * WEC;
  bf16_t* Qp = wob + WEC;           // Qp|Kp contiguous (QK output segments)
  bf16_t* Kp = Qp + NEC;
  bf16_t* Vt = Kp + NEC;
  bf16_t* AO = Vt + NEC;
  // workspace: (4*WEC + 4*NEC)*2 = 72 MiB

  cast_w<<<dim3((unsigned)(4 * WEC / 8 / 256)), dim3(256), 0, stream>>>(
      Wq, Wk, Wv, Wo, wqb);

  const float cexp = 0.18033688f; // log2(e)/8, folded into Q projection
  gemm_qkv<<<dim3(768), dim3(512), 0, stream>>>(query, key_i, value, wqb,
                                                bq, bk, bv, cexp, Qp, Vt);

  attn_kernel<<<dim3(4 * HEADS * (SEQ / 256)), 512, 0, stream>>>(Qp, Kp, Vt, AO);

  gemm_out<<<dim3(512), dim3(256), 0, stream>>>(AO, wob, bo, out);
}